// Round 14
// baseline (426.940 us; speedup 1.0000x reference)
//
#include <hip/hip_runtime.h>
#include <math.h>

#define N_NODES 50000
#define D_MODEL 128
#define N_HEADS 8
#define HEAD_C 16
#define E_DIM 16
#define N_EDGES 800000

typedef __attribute__((ext_vector_type(8))) short bf16x8;
typedef __attribute__((ext_vector_type(4))) float f32x4;

__device__ inline ushort f2bf(float f) {
    unsigned u = __float_as_uint(f);
    unsigned r = (u + 0x7fffu + ((u >> 16) & 1u)) >> 16;
    return (ushort)r;
}
__device__ inline float bf2f(ushort h) { return __uint_as_float(((unsigned)h) << 16); }
__device__ inline uint pack2(float a, float b) {
    return (uint)f2bf(a) | ((uint)f2bf(b) << 16);
}
__device__ inline float gelu_f(float v) {
    return 0.5f * v * (1.0f + erff(v * 0.70710678118654752f));
}

// ---------------- Weight prep: transpose + bf16 cast (+ zero deg) ----------------
__global__ void prep_weights(const float* __restrict__ wq, const float* __restrict__ wk,
                             const float* __restrict__ wv, const float* __restrict__ wsk,
                             const float* __restrict__ bq, const float* __restrict__ bk,
                             const float* __restrict__ bv, const float* __restrict__ bsk,
                             const float* __restrict__ w1, const float* __restrict__ w2,
                             ushort* __restrict__ wqkvsT, float* __restrict__ bqkvs,
                             ushort* __restrict__ w1T, ushort* __restrict__ w2T,
                             int* __restrict__ deg)
{
    int idx = blockIdx.x * 256 + threadIdx.x;          // 0..65535
    {   // wqkvsT [512][128] <- {wq|wk|wv|wsk}[128][128] transposed
        int m = idx >> 7, kk = idx & 127;
        int b = m >> 7, ch = m & 127;
        const float* src = (b == 0) ? wq : (b == 1) ? wk : (b == 2) ? wv : wsk;
        wqkvsT[idx] = f2bf(src[kk * 128 + ch]);
    }
    if (idx < 256 * 128) {   // w1T [256][128] <- w1[128][256]
        int m = idx >> 7, k = idx & 127;
        w1T[idx] = f2bf(w1[k * 256 + m]);
    }
    if (idx < 128 * 256) {   // w2T [128][256] <- w2[256][128]
        int m = idx >> 8, k = idx & 255;
        w2T[idx] = f2bf(w2[k * 128 + m]);
    }
    if (idx < 512) {
        int b = idx >> 7, ch = idx & 127;
        const float* bb = (b == 0) ? bq : (b == 1) ? bk : (b == 2) ? bv : bsk;
        bqkvs[idx] = bb[ch];
    }
    if (idx < N_NODES) deg[idx] = 0;   // replaces hipMemsetAsync dispatch
}

// ---------------- Fused LN1 + projection GEMM (K=128, M=512, BN=128) ----------------
__global__ __launch_bounds__(256) void proj_ln_gemm(
    const float* __restrict__ X, const float* __restrict__ ln_g, const float* __restrict__ ln_b,
    const ushort* __restrict__ WT, const float* __restrict__ bias,
    ushort* __restrict__ Y, int nrows)
{
    __shared__ __align__(16) ushort Al[128 * 128];   // 32 KB
    __shared__ __align__(16) ushort Wl[128 * 128];   // 32 KB
    int tid = threadIdx.x;
    int wv = tid >> 6, lane = tid & 63;
    int row0 = blockIdx.x * 128;
    int col0 = blockIdx.y * 128;

    int c16 = tid & 15;
    float4 g0 = *(const float4*)&ln_g[c16 * 8];
    float4 g1 = *(const float4*)&ln_g[c16 * 8 + 4];
    float4 bb0 = *(const float4*)&ln_b[c16 * 8];
    float4 bb1 = *(const float4*)&ln_b[c16 * 8 + 4];

    #pragma unroll
    for (int i = 0; i < 8; ++i) {
        int c = tid + i * 256;
        int r = c >> 4;
        int gr = row0 + r;
        float4 xa = make_float4(0.f, 0.f, 0.f, 0.f), xb = xa;
        if (gr < nrows) {
            xa = *(const float4*)&X[(size_t)gr * 128 + c16 * 8];
            xb = *(const float4*)&X[(size_t)gr * 128 + c16 * 8 + 4];
        }
        float s  = xa.x + xa.y + xa.z + xa.w + xb.x + xb.y + xb.z + xb.w;
        float ss = xa.x*xa.x + xa.y*xa.y + xa.z*xa.z + xa.w*xa.w
                 + xb.x*xb.x + xb.y*xb.y + xb.z*xb.z + xb.w*xb.w;
        #pragma unroll
        for (int m = 1; m < 16; m <<= 1) {
            s  += __shfl_xor(s,  m, 64);
            ss += __shfl_xor(ss, m, 64);
        }
        float mu  = s * (1.0f / 128.0f);
        float var = ss * (1.0f / 128.0f) - mu * mu;
        float rs  = rsqrtf(var + 1e-5f);
        ushort h[8];
        h[0] = f2bf((xa.x - mu) * rs * g0.x + bb0.x);
        h[1] = f2bf((xa.y - mu) * rs * g0.y + bb0.y);
        h[2] = f2bf((xa.z - mu) * rs * g0.z + bb0.z);
        h[3] = f2bf((xa.w - mu) * rs * g0.w + bb0.w);
        h[4] = f2bf((xb.x - mu) * rs * g1.x + bb1.x);
        h[5] = f2bf((xb.y - mu) * rs * g1.y + bb1.y);
        h[6] = f2bf((xb.z - mu) * rs * g1.z + bb1.z);
        h[7] = f2bf((xb.w - mu) * rs * g1.w + bb1.w);
        int byte = r * 256 + ((c16 * 16) ^ ((r & 7) << 4));
        *(ulonglong2*)((char*)Al + byte) = *(ulonglong2*)h;
    }
    #pragma unroll
    for (int i = 0; i < 8; ++i) {
        int c = tid + i * 256;
        int r = c >> 4, cc = c & 15;
        ulonglong2 val = *(const ulonglong2*)(WT + (size_t)(col0 + r) * 128 + cc * 8);
        int byte = r * 256 + ((cc * 16) ^ ((r & 7) << 4));
        *(ulonglong2*)((char*)Wl + byte) = val;
    }
    __syncthreads();

    f32x4 acc[2][8];
    #pragma unroll
    for (int i = 0; i < 2; ++i)
        #pragma unroll
        for (int j = 0; j < 8; ++j) acc[i][j] = (f32x4){0.f, 0.f, 0.f, 0.f};
    #pragma unroll
    for (int ks = 0; ks < 4; ++ks) {
        bf16x8 af[2], bfr[8];
        #pragma unroll
        for (int rt = 0; rt < 2; ++rt) {
            int r = wv * 32 + rt * 16 + (lane & 15);
            int byte = r * 256 + ((ks * 64 + (lane >> 4) * 16) ^ ((r & 7) << 4));
            af[rt] = *(const bf16x8*)((const char*)Al + byte);
        }
        #pragma unroll
        for (int ct = 0; ct < 8; ++ct) {
            int r = ct * 16 + (lane & 15);
            int byte = r * 256 + ((ks * 64 + (lane >> 4) * 16) ^ ((r & 7) << 4));
            bfr[ct] = *(const bf16x8*)((const char*)Wl + byte);
        }
        #pragma unroll
        for (int rt = 0; rt < 2; ++rt)
            #pragma unroll
            for (int ct = 0; ct < 8; ++ct)
                acc[rt][ct] = __builtin_amdgcn_mfma_f32_16x16x32_bf16(
                    af[rt], bfr[ct], acc[rt][ct], 0, 0, 0);
    }
    #pragma unroll
    for (int rt = 0; rt < 2; ++rt) {
        #pragma unroll
        for (int ct = 0; ct < 8; ++ct) {
            int gcol = col0 + ct * 16 + (lane & 15);
            float bv = bias[gcol];
            #pragma unroll
            for (int r = 0; r < 4; ++r) {
                int grow = row0 + wv * 32 + rt * 16 + (lane >> 4) * 4 + r;
                if (grow >= nrows) continue;
                Y[(size_t)grow * 512 + gcol] = f2bf(acc[rt][ct][r] + bv);
            }
        }
    }
}

// ---------------- Repack k,v pairs -> one uint2 per lane per node (bf16, exact) ---
// kv16[node*64 + l] = { k-pair uint (ch 2l,2l+1), v-pair uint (ch 2l,2l+1) }
__global__ void repack_kv(const ushort* __restrict__ qkvs, uint2* __restrict__ kv16)
{
    int idx = blockIdx.x * 256 + threadIdx.x;
    if (idx >= N_NODES * 64) return;
    int node = idx >> 6, u = idx & 63;
    size_t nb = (size_t)node * 512;
    uint kp = *(const uint*)(qkvs + nb + 128 + 2 * u);
    uint vp = *(const uint*)(qkvs + nb + 256 + 2 * u);
    kv16[idx] = make_uint2(kp, vp);
}

// ---------------- Fused FFN, K-split (r12 proven) ----------------
__global__ __launch_bounds__(256) void ffn_fused(
    const ushort* __restrict__ A, const ushort* __restrict__ W1T,
    const ushort* __restrict__ W2T, const float* __restrict__ b1,
    const float* __restrict__ b2, const float* __restrict__ xnew,
    float* __restrict__ out, int nrows)
{
    __shared__ __align__(16) ushort Xl[128 * 128];   // 32 KB
    __shared__ __align__(16) ushort W1l[64 * 128];   // 16 KB
    __shared__ __align__(16) ushort Hl[128 * 64];    // 16 KB
    __shared__ __align__(16) ushort W2l[128 * 64];   // 16 KB
    int tid = threadIdx.x;
    int wv = tid >> 6, lane = tid & 63;
    int row0 = blockIdx.x * 128;

    #pragma unroll
    for (int i = 0; i < 8; ++i) {
        int c = tid + i * 256;
        int r = c >> 4, c16 = c & 15;
        int gr = row0 + r;
        ulonglong2 val = {0ull, 0ull};
        if (gr < nrows) val = *(const ulonglong2*)(A + (size_t)gr * 128 + c16 * 8);
        int byte = r * 256 + ((c16 * 16) ^ ((r & 7) << 4));
        *(ulonglong2*)((char*)Xl + byte) = val;
    }

    f32x4 acc2[2][8];
    #pragma unroll
    for (int i = 0; i < 2; ++i)
        #pragma unroll
        for (int j = 0; j < 8; ++j) acc2[i][j] = (f32x4){0.f, 0.f, 0.f, 0.f};

    for (int q = 0; q < 4; ++q) {
        #pragma unroll
        for (int i = 0; i < 4; ++i) {
            int c = tid + i * 256;
            int r = c >> 4, cc = c & 15;
            ulonglong2 val = *(const ulonglong2*)(W1T + (size_t)(q * 64 + r) * 128 + cc * 8);
            int byte = r * 256 + ((cc * 16) ^ ((r & 7) << 4));
            *(ulonglong2*)((char*)W1l + byte) = val;
        }
        #pragma unroll
        for (int i = 0; i < 4; ++i) {
            int c = tid + i * 256;
            int r = c >> 3, c8 = c & 7;
            ulonglong2 val = *(const ulonglong2*)(W2T + (size_t)r * 256 + q * 64 + c8 * 8);
            int byte = r * 128 + ((c8 * 16) ^ ((r & 7) << 4));
            *(ulonglong2*)((char*)W2l + byte) = val;
        }
        __syncthreads();

        f32x4 acc1[2][4];
        #pragma unroll
        for (int i = 0; i < 2; ++i)
            #pragma unroll
            for (int j = 0; j < 4; ++j) acc1[i][j] = (f32x4){0.f, 0.f, 0.f, 0.f};
        #pragma unroll
        for (int ks = 0; ks < 4; ++ks) {
            bf16x8 af[2], bfr[4];
            #pragma unroll
            for (int rt = 0; rt < 2; ++rt) {
                int r = wv * 32 + rt * 16 + (lane & 15);
                int byte = r * 256 + ((ks * 64 + (lane >> 4) * 16) ^ ((r & 7) << 4));
                af[rt] = *(const bf16x8*)((const char*)Xl + byte);
            }
            #pragma unroll
            for (int ct = 0; ct < 4; ++ct) {
                int r = ct * 16 + (lane & 15);
                int byte = r * 256 + ((ks * 64 + (lane >> 4) * 16) ^ ((r & 7) << 4));
                bfr[ct] = *(const bf16x8*)((const char*)W1l + byte);
            }
            #pragma unroll
            for (int rt = 0; rt < 2; ++rt)
                #pragma unroll
                for (int ct = 0; ct < 4; ++ct)
                    acc1[rt][ct] = __builtin_amdgcn_mfma_f32_16x16x32_bf16(
                        af[rt], bfr[ct], acc1[rt][ct], 0, 0, 0);
        }
        #pragma unroll
        for (int rt = 0; rt < 2; ++rt) {
            #pragma unroll
            for (int ct = 0; ct < 4; ++ct) {
                int cl = ct * 16 + (lane & 15);
                float bv = b1[q * 64 + cl];
                #pragma unroll
                for (int r = 0; r < 4; ++r) {
                    int row = wv * 32 + rt * 16 + (lane >> 4) * 4 + r;
                    float v = gelu_f(acc1[rt][ct][r] + bv);
                    int cb = cl * 2;
                    int byte = row * 128 + ((cb & ~15) ^ ((row & 7) << 4)) + (cb & 15);
                    *(ushort*)((char*)Hl + byte) = f2bf(v);
                }
            }
        }
        __syncthreads();

        #pragma unroll
        for (int ks = 0; ks < 2; ++ks) {
            bf16x8 af[2], bfr[8];
            #pragma unroll
            for (int rt = 0; rt < 2; ++rt) {
                int row = wv * 32 + rt * 16 + (lane & 15);
                int byte = row * 128 + ((ks * 64 + (lane >> 4) * 16) ^ ((row & 7) << 4));
                af[rt] = *(const bf16x8*)((const char*)Hl + byte);
            }
            #pragma unroll
            for (int ct = 0; ct < 8; ++ct) {
                int r = ct * 16 + (lane & 15);
                int byte = r * 128 + ((ks * 64 + (lane >> 4) * 16) ^ ((r & 7) << 4));
                bfr[ct] = *(const bf16x8*)((const char*)W2l + byte);
            }
            #pragma unroll
            for (int rt = 0; rt < 2; ++rt)
                #pragma unroll
                for (int ct = 0; ct < 8; ++ct)
                    acc2[rt][ct] = __builtin_amdgcn_mfma_f32_16x16x32_bf16(
                        af[rt], bfr[ct], acc2[rt][ct], 0, 0, 0);
        }
        __syncthreads();
    }

    #pragma unroll
    for (int rt = 0; rt < 2; ++rt) {
        #pragma unroll
        for (int ct = 0; ct < 8; ++ct) {
            int gcol = ct * 16 + (lane & 15);
            float bv = b2[gcol];
            #pragma unroll
            for (int r = 0; r < 4; ++r) {
                int grow = row0 + wv * 32 + rt * 16 + (lane >> 4) * 4 + r;
                if (grow >= nrows) continue;
                size_t idx = (size_t)grow * 128 + gcol;
                out[idx] = acc2[rt][ct][r] + bv + xnew[idx];
            }
        }
    }
}

// ---------------- Counting sort of edges by destination ----------------
__global__ void hist_kernel(const int* __restrict__ dst, int* __restrict__ deg)
{
    int e = blockIdx.x * 256 + threadIdx.x;
    if (e < N_EDGES) atomicAdd(&deg[dst[e]], 1);
}

// single-block fused exclusive scan (replaces scan1+scan2+scan3)
__global__ __launch_bounds__(1024) void scan_fused(const int* __restrict__ deg,
                                                   int* __restrict__ off,
                                                   int* __restrict__ cursor)
{
    __shared__ int part[1024];
    const int CH = (N_NODES + 1023) / 1024;   // 49
    int t = threadIdx.x;
    int base = t * CH;
    int sum = 0;
    for (int i = 0; i < CH; ++i) {
        int idx = base + i;
        if (idx < N_NODES) sum += deg[idx];
    }
    part[t] = sum;
    __syncthreads();
    for (int d = 1; d < 1024; d <<= 1) {
        int v = (t >= d) ? part[t - d] : 0;
        __syncthreads();
        part[t] += v;
        __syncthreads();
    }
    int run = (t > 0) ? part[t - 1] : 0;
    for (int i = 0; i < CH; ++i) {
        int idx = base + i;
        if (idx < N_NODES) {
            off[idx] = run;
            cursor[idx] = run;
            run += deg[idx];
        }
    }
}

// scatter: src id + bf16 edge_attr row in destination-sorted order
// (random writes here buy SEQUENTIAL hot-loop reads in node_attn — r6 lesson)
__global__ void scatter_kernel(const int* __restrict__ dst, const int* __restrict__ src,
                               const float* __restrict__ eattr, int* __restrict__ cursor,
                               int* __restrict__ src_s, ushort* __restrict__ eattr_s)
{
    int e = blockIdx.x * 256 + threadIdx.x;
    if (e < N_EDGES) {
        int p = atomicAdd(&cursor[dst[e]], 1);
        src_s[p] = src[e];
        const float4* s4 = (const float4*)(eattr + (size_t)e * E_DIM);
        float4 f0 = s4[0], f1 = s4[1], f2 = s4[2], f3 = s4[3];
        uint4 u0, u1;
        u0.x = pack2(f0.x, f0.y); u0.y = pack2(f0.z, f0.w);
        u0.z = pack2(f1.x, f1.y); u0.w = pack2(f1.z, f1.w);
        u1.x = pack2(f2.x, f2.y); u1.y = pack2(f2.z, f2.w);
        u1.z = pack2(f3.x, f3.y); u1.w = pack2(f3.z, f3.w);
        uint4* d4 = (uint4*)(eattr_s + (size_t)p * E_DIM);
        d4[0] = u0; d4[1] = u1;
    }
}

// ---------------- Fused node attention + beta + residual + LN2 ----------
// r9 loop skeleton (dual-state 2-way unroll — do not restructure; r8/r10 lessons).
// k/v gathered as ONE uint2 per lane (bf16 exact, single load + single addr chain).
#define ATTN_STEP(P, S, A0, A1, E0, E1) do {                                         \
    int sv_ = src_s[P];                                                              \
    uint eap_ = *(const uint*)(eattr_s + (size_t)(P) * E_DIM + j2);                  \
    float ea0_ = bf2f((ushort)eap_), ea1_ = bf2f((ushort)(eap_ >> 16));              \
    uint2 kv_ = kv16[(size_t)sv_ * 64 + lane];                                       \
    float p_ = q0 * bf2f((ushort)kv_.x) + q1 * bf2f((ushort)(kv_.x >> 16))           \
             + ea0_ * qp0 + ea1_ * qp1;                                              \
    p_ += __shfl_xor(p_, 1, 64);                                                     \
    p_ += __shfl_xor(p_, 2, 64);                                                     \
    p_ += __shfl_xor(p_, 4, 64);                                                     \
    float w_ = __expf(fminf(p_, 60.f));                                              \
    S  += w_;                                                                        \
    A0 += w_ * bf2f((ushort)kv_.y);                                                  \
    A1 += w_ * bf2f((ushort)(kv_.y >> 16));                                          \
    E0 += w_ * ea0_;                                                                 \
    E1 += w_ * ea1_;                                                                 \
} while (0)

__global__ void node_attn(const ushort* __restrict__ qkvs, const uint2* __restrict__ kv16,
                          const float* __restrict__ x,
                          const float* __restrict__ we, const float* __restrict__ wbeta,
                          const float* __restrict__ ln2g, const float* __restrict__ ln2b,
                          const int* __restrict__ off, const int* __restrict__ deg,
                          const int* __restrict__ src_s, const ushort* __restrict__ eattr_s,
                          float* __restrict__ xnew, ushort* __restrict__ h2)
{
    __shared__ float wl[E_DIM * 128];     // we row-major [16][128], 8 KB
    __shared__ float weT[128 * 17];       // we transposed [128][16+pad], 8.5 KB
    __shared__ float sc4[4][128];         // per-wave scratch, 2 KB
    for (int t = threadIdx.x; t < E_DIM * 32; t += 256)
        *(float4*)&wl[t * 4] = *(const float4*)&we[t * 4];
    for (int t = threadIdx.x; t < E_DIM * 128; t += 256) {
        int j = t >> 7, ch = t & 127;
        weT[ch * 17 + j] = we[t];
    }
    __syncthreads();

    int nl   = threadIdx.x >> 6;
    int node = blockIdx.x * 4 + nl;
    int lane = threadIdx.x & 63;
    if (node >= N_NODES) return;

    int j2 = (lane & 7) * 2;              // this lane's ea component pair
    int hb = (lane >> 3) * 16;            // head channel base

    size_t nb = (size_t)node * 512;
    uint qp = *(const uint*)(qkvs + nb + 2 * lane);
    float q0r = bf2f((ushort)qp), q1r = bf2f((ushort)(qp >> 16));

    sc4[nl][2 * lane]     = q0r;
    sc4[nl][2 * lane + 1] = q1r;
    float qp0 = 0.f, qp1 = 0.f;
    #pragma unroll
    for (int c = 0; c < 16; ++c) {
        float qc = sc4[nl][hb + c];
        qp0 += qc * weT[(hb + c) * 17 + j2];
        qp1 += qc * weT[(hb + c) * 17 + j2 + 1];
    }
    float q0 = q0r * 0.25f, q1 = q1r * 0.25f;   // fold 1/sqrt(C)
    qp0 *= 0.25f; qp1 *= 0.25f;

    float SA = 0.f, A0a = 0.f, A1a = 0.f, E0a = 0.f, E1a = 0.f;
    float SB = 0.f, A0b = 0.f, A1b = 0.f, E0b = 0.f, E1b = 0.f;

    int o = off[node], dg = deg[node];
    int i = 0;
    for (; i + 2 <= dg; i += 2) {
        ATTN_STEP(o + i,     SA, A0a, A1a, E0a, E1a);
        ATTN_STEP(o + i + 1, SB, A0b, A1b, E0b, E1b);
    }
    if (i < dg)
        ATTN_STEP(o + i, SA, A0a, A1a, E0a, E1a);

    float S  = SA + SB;
    float A0 = A0a + A0b, A1 = A1a + A1b;
    float E0 = E0a + E0b, E1 = E1a + E1b;

    sc4[nl][2 * lane]     = E0;
    sc4[nl][2 * lane + 1] = E1;
    float ep0 = 0.f, ep1 = 0.f;
    #pragma unroll
    for (int j = 0; j < 16; ++j) {
        float es = sc4[nl][hb + j];
        ep0 += es * wl[j * 128 + 2 * lane];
        ep1 += es * wl[j * 128 + 2 * lane + 1];
    }

    float rinv = 1.f / (S + 1e-16f);
    float o0 = (A0 + ep0) * rinv;
    float o1 = (A1 + ep1) * rinv;

    uint xrp = *(const uint*)(qkvs + nb + 384 + 2 * lane);
    float xr0 = bf2f((ushort)xrp), xr1 = bf2f((ushort)(xrp >> 16));
    float2 wb0 = *(const float2*)&wbeta[2 * lane];
    float2 wb1 = *(const float2*)&wbeta[128 + 2 * lane];
    float2 wb2 = *(const float2*)&wbeta[256 + 2 * lane];
    float dot = o0 * wb0.x + o1 * wb0.y + xr0 * wb1.x + xr1 * wb1.y
              + (o0 - xr0) * wb2.x + (o1 - xr1) * wb2.y;
    #pragma unroll
    for (int w = 32; w > 0; w >>= 1) dot += __shfl_xor(dot, w, 64);
    float beta = 1.f / (1.f + __expf(-dot));

    size_t xb = (size_t)node * D_MODEL + 2 * lane;
    float2 xv = *(const float2*)&x[xb];
    float ox = xv.x + beta * xr0 + (1.f - beta) * o0;
    float oy = xv.y + beta * xr1 + (1.f - beta) * o1;
    *(float2*)&xnew[xb] = make_float2(ox, oy);

    // ---- fused LN2 ----
    float s2  = ox + oy;
    float ss2 = ox * ox + oy * oy;
    #pragma unroll
    for (int w = 32; w > 0; w >>= 1) {
        s2  += __shfl_xor(s2,  w, 64);
        ss2 += __shfl_xor(ss2, w, 64);
    }
    float mu  = s2 * (1.0f / 128.0f);
    float var = ss2 * (1.0f / 128.0f) - mu * mu;
    float rs  = rsqrtf(var + 1e-5f);
    float2 g2 = *(const float2*)&ln2g[2 * lane];
    float2 b2 = *(const float2*)&ln2b[2 * lane];
    float h0 = (ox - mu) * rs * g2.x + b2.x;
    float h1 = (oy - mu) * rs * g2.y + b2.y;
    ((uint*)h2)[(size_t)node * 64 + lane] = pack2(h0, h1);
}

extern "C" void kernel_launch(void* const* d_in, const int* in_sizes, int n_in,
                              void* d_out, int out_size, void* d_ws, size_t ws_size,
                              hipStream_t stream)
{
    const float* x     = (const float*)d_in[0];
    const int*   eidx  = (const int*)  d_in[1];
    const float* eattr = (const float*)d_in[2];
    const float* wq  = (const float*)d_in[3];  const float* bq  = (const float*)d_in[4];
    const float* wk  = (const float*)d_in[5];  const float* bk  = (const float*)d_in[6];
    const float* wv  = (const float*)d_in[7];  const float* bv  = (const float*)d_in[8];
    const float* we  = (const float*)d_in[9];
    const float* wsk = (const float*)d_in[10]; const float* bsk = (const float*)d_in[11];
    const float* wbeta = (const float*)d_in[12];
    const float* ln1g = (const float*)d_in[13]; const float* ln1b = (const float*)d_in[14];
    const float* ln2g = (const float*)d_in[15]; const float* ln2b = (const float*)d_in[16];
    const float* w1 = (const float*)d_in[17]; const float* b1 = (const float*)d_in[18];
    const float* w2 = (const float*)d_in[19]; const float* b2 = (const float*)d_in[20];
    const int* srcp = eidx;
    const int* dstp = eidx + N_EDGES;
    float* out = (float*)d_out;

    char* w = (char*)d_ws;
    size_t o = 0;
    ushort* qkvs_b  = (ushort*)(w + o);  o += (size_t)N_NODES * 512 * 2;   // 51.2MB
    float* xnew = (float*)(w + o);  o += (size_t)N_NODES * 128 * 4;        // 25.6MB
    ushort* eattr_s = (ushort*)(w + o); o += (size_t)N_EDGES * E_DIM * 2;  // 25.6MB
    int* src_s = (int*)(w + o);     o += (size_t)N_EDGES * 4;              // 3.2MB
    ushort* h2_b = (ushort*)(w + o); o += (size_t)N_NODES * 128 * 2;       // 12.8MB
    uint2* kv16 = (uint2*)(w + o);  o += (size_t)N_NODES * 64 * 8;         // 25.6MB
    ushort* wqkvsT = (ushort*)(w + o); o += 512 * 128 * 2;
    ushort* w1T    = (ushort*)(w + o); o += 256 * 128 * 2;
    ushort* w2T    = (ushort*)(w + o); o += 128 * 256 * 2;
    float*  bqkvs  = (float*)(w + o);  o += 4096;
    int* deg    = (int*)(w + o); o += 200704;
    int* offb   = (int*)(w + o); o += 200704;
    int* cursor = (int*)(w + o); o += 200704;

    dim3 blk(256);
    dim3 lngrid((N_NODES + 3) / 4);
    const int EB = (N_EDGES + 255) / 256;
    const int GB = (N_NODES + 127) / 128;

    prep_weights<<<dim3(256), blk, 0, stream>>>(wq, wk, wv, wsk, bq, bk, bv, bsk,
                                                w1, w2, wqkvsT, bqkvs, w1T, w2T, deg);
    proj_ln_gemm<<<dim3(GB, 4), blk, 0, stream>>>(x, ln1g, ln1b, wqkvsT, bqkvs,
                                                  qkvs_b, N_NODES);
    repack_kv<<<dim3((N_NODES * 64 + 255) / 256), blk, 0, stream>>>(qkvs_b, kv16);
    hist_kernel<<<dim3(EB), blk, 0, stream>>>(dstp, deg);
    scan_fused<<<dim3(1), dim3(1024), 0, stream>>>(deg, offb, cursor);
    scatter_kernel<<<dim3(EB), blk, 0, stream>>>(dstp, srcp, eattr, cursor, src_s, eattr_s);
    node_attn<<<lngrid, blk, 0, stream>>>(qkvs_b, kv16, x, we, wbeta, ln2g, ln2b,
                                          offb, deg, src_s, eattr_s, xnew, h2_b);
    ffn_fused<<<dim3(GB), blk, 0, stream>>>(h2_b, w1T, w2T, b1, b2, xnew, out, N_NODES);
}

// Round 15
// 295.783 us; speedup vs baseline: 1.4434x; 1.4434x over previous
//
#include <hip/hip_runtime.h>
#include <math.h>

#define N_NODES 50000
#define D_MODEL 128
#define N_HEADS 8
#define HEAD_C 16
#define E_DIM 16
#define N_EDGES 800000

typedef __attribute__((ext_vector_type(8))) short bf16x8;
typedef __attribute__((ext_vector_type(4))) float f32x4;

__device__ inline ushort f2bf(float f) {
    unsigned u = __float_as_uint(f);
    unsigned r = (u + 0x7fffu + ((u >> 16) & 1u)) >> 16;
    return (ushort)r;
}
__device__ inline float bf2f(ushort h) { return __uint_as_float(((unsigned)h) << 16); }
__device__ inline uint pack2(float a, float b) {
    return (uint)f2bf(a) | ((uint)f2bf(b) << 16);
}
__device__ inline float gelu_f(float v) {
    return 0.5f * v * (1.0f + erff(v * 0.70710678118654752f));
}

// ---------------- Weight prep: transpose + bf16 cast (+ zero deg) ----------------
__global__ void prep_weights(const float* __restrict__ wq, const float* __restrict__ wk,
                             const float* __restrict__ wv, const float* __restrict__ wsk,
                             const float* __restrict__ bq, const float* __restrict__ bk,
                             const float* __restrict__ bv, const float* __restrict__ bsk,
                             const float* __restrict__ w1, const float* __restrict__ w2,
                             ushort* __restrict__ wqkvsT, float* __restrict__ bqkvs,
                             ushort* __restrict__ w1T, ushort* __restrict__ w2T,
                             int* __restrict__ deg)
{
    int idx = blockIdx.x * 256 + threadIdx.x;          // 0..65535
    {   // wqkvsT [512][128] <- {wq|wk|wv|wsk}[128][128] transposed
        int m = idx >> 7, kk = idx & 127;
        int b = m >> 7, ch = m & 127;
        const float* src = (b == 0) ? wq : (b == 1) ? wk : (b == 2) ? wv : wsk;
        wqkvsT[idx] = f2bf(src[kk * 128 + ch]);
    }
    if (idx < 256 * 128) {   // w1T [256][128] <- w1[128][256]
        int m = idx >> 7, k = idx & 127;
        w1T[idx] = f2bf(w1[k * 256 + m]);
    }
    if (idx < 128 * 256) {   // w2T [128][256] <- w2[256][128]
        int m = idx >> 8, k = idx & 255;
        w2T[idx] = f2bf(w2[k * 128 + m]);
    }
    if (idx < 512) {
        int b = idx >> 7, ch = idx & 127;
        const float* bb = (b == 0) ? bq : (b == 1) ? bk : (b == 2) ? bv : bsk;
        bqkvs[idx] = bb[ch];
    }
    if (idx < N_NODES) deg[idx] = 0;   // replaces hipMemsetAsync dispatch
}

// ---------------- Fused LN1 + projection GEMM (K=128, M=512, BN=128) ----------------
__global__ __launch_bounds__(256) void proj_ln_gemm(
    const float* __restrict__ X, const float* __restrict__ ln_g, const float* __restrict__ ln_b,
    const ushort* __restrict__ WT, const float* __restrict__ bias,
    ushort* __restrict__ Y, int nrows)
{
    __shared__ __align__(16) ushort Al[128 * 128];   // 32 KB
    __shared__ __align__(16) ushort Wl[128 * 128];   // 32 KB
    int tid = threadIdx.x;
    int wv = tid >> 6, lane = tid & 63;
    int row0 = blockIdx.x * 128;
    int col0 = blockIdx.y * 128;

    int c16 = tid & 15;
    float4 g0 = *(const float4*)&ln_g[c16 * 8];
    float4 g1 = *(const float4*)&ln_g[c16 * 8 + 4];
    float4 bb0 = *(const float4*)&ln_b[c16 * 8];
    float4 bb1 = *(const float4*)&ln_b[c16 * 8 + 4];

    #pragma unroll
    for (int i = 0; i < 8; ++i) {
        int c = tid + i * 256;
        int r = c >> 4;
        int gr = row0 + r;
        float4 xa = make_float4(0.f, 0.f, 0.f, 0.f), xb = xa;
        if (gr < nrows) {
            xa = *(const float4*)&X[(size_t)gr * 128 + c16 * 8];
            xb = *(const float4*)&X[(size_t)gr * 128 + c16 * 8 + 4];
        }
        float s  = xa.x + xa.y + xa.z + xa.w + xb.x + xb.y + xb.z + xb.w;
        float ss = xa.x*xa.x + xa.y*xa.y + xa.z*xa.z + xa.w*xa.w
                 + xb.x*xb.x + xb.y*xb.y + xb.z*xb.z + xb.w*xb.w;
        #pragma unroll
        for (int m = 1; m < 16; m <<= 1) {
            s  += __shfl_xor(s,  m, 64);
            ss += __shfl_xor(ss, m, 64);
        }
        float mu  = s * (1.0f / 128.0f);
        float var = ss * (1.0f / 128.0f) - mu * mu;
        float rs  = rsqrtf(var + 1e-5f);
        ushort h[8];
        h[0] = f2bf((xa.x - mu) * rs * g0.x + bb0.x);
        h[1] = f2bf((xa.y - mu) * rs * g0.y + bb0.y);
        h[2] = f2bf((xa.z - mu) * rs * g0.z + bb0.z);
        h[3] = f2bf((xa.w - mu) * rs * g0.w + bb0.w);
        h[4] = f2bf((xb.x - mu) * rs * g1.x + bb1.x);
        h[5] = f2bf((xb.y - mu) * rs * g1.y + bb1.y);
        h[6] = f2bf((xb.z - mu) * rs * g1.z + bb1.z);
        h[7] = f2bf((xb.w - mu) * rs * g1.w + bb1.w);
        int byte = r * 256 + ((c16 * 16) ^ ((r & 7) << 4));
        *(ulonglong2*)((char*)Al + byte) = *(ulonglong2*)h;
    }
    #pragma unroll
    for (int i = 0; i < 8; ++i) {
        int c = tid + i * 256;
        int r = c >> 4, cc = c & 15;
        ulonglong2 val = *(const ulonglong2*)(WT + (size_t)(col0 + r) * 128 + cc * 8);
        int byte = r * 256 + ((cc * 16) ^ ((r & 7) << 4));
        *(ulonglong2*)((char*)Wl + byte) = val;
    }
    __syncthreads();

    f32x4 acc[2][8];
    #pragma unroll
    for (int i = 0; i < 2; ++i)
        #pragma unroll
        for (int j = 0; j < 8; ++j) acc[i][j] = (f32x4){0.f, 0.f, 0.f, 0.f};
    #pragma unroll
    for (int ks = 0; ks < 4; ++ks) {
        bf16x8 af[2], bfr[8];
        #pragma unroll
        for (int rt = 0; rt < 2; ++rt) {
            int r = wv * 32 + rt * 16 + (lane & 15);
            int byte = r * 256 + ((ks * 64 + (lane >> 4) * 16) ^ ((r & 7) << 4));
            af[rt] = *(const bf16x8*)((const char*)Al + byte);
        }
        #pragma unroll
        for (int ct = 0; ct < 8; ++ct) {
            int r = ct * 16 + (lane & 15);
            int byte = r * 256 + ((ks * 64 + (lane >> 4) * 16) ^ ((r & 7) << 4));
            bfr[ct] = *(const bf16x8*)((const char*)Wl + byte);
        }
        #pragma unroll
        for (int rt = 0; rt < 2; ++rt)
            #pragma unroll
            for (int ct = 0; ct < 8; ++ct)
                acc[rt][ct] = __builtin_amdgcn_mfma_f32_16x16x32_bf16(
                    af[rt], bfr[ct], acc[rt][ct], 0, 0, 0);
    }
    #pragma unroll
    for (int rt = 0; rt < 2; ++rt) {
        #pragma unroll
        for (int ct = 0; ct < 8; ++ct) {
            int gcol = col0 + ct * 16 + (lane & 15);
            float bv = bias[gcol];
            #pragma unroll
            for (int r = 0; r < 4; ++r) {
                int grow = row0 + wv * 32 + rt * 16 + (lane >> 4) * 4 + r;
                if (grow >= nrows) continue;
                Y[(size_t)grow * 512 + gcol] = f2bf(acc[rt][ct][r] + bv);
            }
        }
    }
}

// ---------------- Fused FFN, K-split (r12 proven) ----------------
__global__ __launch_bounds__(256) void ffn_fused(
    const ushort* __restrict__ A, const ushort* __restrict__ W1T,
    const ushort* __restrict__ W2T, const float* __restrict__ b1,
    const float* __restrict__ b2, const float* __restrict__ xnew,
    float* __restrict__ out, int nrows)
{
    __shared__ __align__(16) ushort Xl[128 * 128];   // 32 KB
    __shared__ __align__(16) ushort W1l[64 * 128];   // 16 KB
    __shared__ __align__(16) ushort Hl[128 * 64];    // 16 KB
    __shared__ __align__(16) ushort W2l[128 * 64];   // 16 KB
    int tid = threadIdx.x;
    int wv = tid >> 6, lane = tid & 63;
    int row0 = blockIdx.x * 128;

    #pragma unroll
    for (int i = 0; i < 8; ++i) {
        int c = tid + i * 256;
        int r = c >> 4, c16 = c & 15;
        int gr = row0 + r;
        ulonglong2 val = {0ull, 0ull};
        if (gr < nrows) val = *(const ulonglong2*)(A + (size_t)gr * 128 + c16 * 8);
        int byte = r * 256 + ((c16 * 16) ^ ((r & 7) << 4));
        *(ulonglong2*)((char*)Xl + byte) = val;
    }

    f32x4 acc2[2][8];
    #pragma unroll
    for (int i = 0; i < 2; ++i)
        #pragma unroll
        for (int j = 0; j < 8; ++j) acc2[i][j] = (f32x4){0.f, 0.f, 0.f, 0.f};

    for (int q = 0; q < 4; ++q) {
        #pragma unroll
        for (int i = 0; i < 4; ++i) {
            int c = tid + i * 256;
            int r = c >> 4, cc = c & 15;
            ulonglong2 val = *(const ulonglong2*)(W1T + (size_t)(q * 64 + r) * 128 + cc * 8);
            int byte = r * 256 + ((cc * 16) ^ ((r & 7) << 4));
            *(ulonglong2*)((char*)W1l + byte) = val;
        }
        #pragma unroll
        for (int i = 0; i < 4; ++i) {
            int c = tid + i * 256;
            int r = c >> 3, c8 = c & 7;
            ulonglong2 val = *(const ulonglong2*)(W2T + (size_t)r * 256 + q * 64 + c8 * 8);
            int byte = r * 128 + ((c8 * 16) ^ ((r & 7) << 4));
            *(ulonglong2*)((char*)W2l + byte) = val;
        }
        __syncthreads();

        f32x4 acc1[2][4];
        #pragma unroll
        for (int i = 0; i < 2; ++i)
            #pragma unroll
            for (int j = 0; j < 4; ++j) acc1[i][j] = (f32x4){0.f, 0.f, 0.f, 0.f};
        #pragma unroll
        for (int ks = 0; ks < 4; ++ks) {
            bf16x8 af[2], bfr[4];
            #pragma unroll
            for (int rt = 0; rt < 2; ++rt) {
                int r = wv * 32 + rt * 16 + (lane & 15);
                int byte = r * 256 + ((ks * 64 + (lane >> 4) * 16) ^ ((r & 7) << 4));
                af[rt] = *(const bf16x8*)((const char*)Xl + byte);
            }
            #pragma unroll
            for (int ct = 0; ct < 4; ++ct) {
                int r = ct * 16 + (lane & 15);
                int byte = r * 256 + ((ks * 64 + (lane >> 4) * 16) ^ ((r & 7) << 4));
                bfr[ct] = *(const bf16x8*)((const char*)W1l + byte);
            }
            #pragma unroll
            for (int rt = 0; rt < 2; ++rt)
                #pragma unroll
                for (int ct = 0; ct < 4; ++ct)
                    acc1[rt][ct] = __builtin_amdgcn_mfma_f32_16x16x32_bf16(
                        af[rt], bfr[ct], acc1[rt][ct], 0, 0, 0);
        }
        #pragma unroll
        for (int rt = 0; rt < 2; ++rt) {
            #pragma unroll
            for (int ct = 0; ct < 4; ++ct) {
                int cl = ct * 16 + (lane & 15);
                float bv = b1[q * 64 + cl];
                #pragma unroll
                for (int r = 0; r < 4; ++r) {
                    int row = wv * 32 + rt * 16 + (lane >> 4) * 4 + r;
                    float v = gelu_f(acc1[rt][ct][r] + bv);
                    int cb = cl * 2;
                    int byte = row * 128 + ((cb & ~15) ^ ((row & 7) << 4)) + (cb & 15);
                    *(ushort*)((char*)Hl + byte) = f2bf(v);
                }
            }
        }
        __syncthreads();

        #pragma unroll
        for (int ks = 0; ks < 2; ++ks) {
            bf16x8 af[2], bfr[8];
            #pragma unroll
            for (int rt = 0; rt < 2; ++rt) {
                int row = wv * 32 + rt * 16 + (lane & 15);
                int byte = row * 128 + ((ks * 64 + (lane >> 4) * 16) ^ ((row & 7) << 4));
                af[rt] = *(const bf16x8*)((const char*)Hl + byte);
            }
            #pragma unroll
            for (int ct = 0; ct < 8; ++ct) {
                int r = ct * 16 + (lane & 15);
                int byte = r * 128 + ((ks * 64 + (lane >> 4) * 16) ^ ((r & 7) << 4));
                bfr[ct] = *(const bf16x8*)((const char*)W2l + byte);
            }
            #pragma unroll
            for (int rt = 0; rt < 2; ++rt)
                #pragma unroll
                for (int ct = 0; ct < 8; ++ct)
                    acc2[rt][ct] = __builtin_amdgcn_mfma_f32_16x16x32_bf16(
                        af[rt], bfr[ct], acc2[rt][ct], 0, 0, 0);
        }
        __syncthreads();
    }

    #pragma unroll
    for (int rt = 0; rt < 2; ++rt) {
        #pragma unroll
        for (int ct = 0; ct < 8; ++ct) {
            int gcol = ct * 16 + (lane & 15);
            float bv = b2[gcol];
            #pragma unroll
            for (int r = 0; r < 4; ++r) {
                int grow = row0 + wv * 32 + rt * 16 + (lane >> 4) * 4 + r;
                if (grow >= nrows) continue;
                size_t idx = (size_t)grow * 128 + gcol;
                out[idx] = acc2[rt][ct][r] + bv + xnew[idx];
            }
        }
    }
}

// ---------------- Counting sort of edges by destination ----------------
__global__ void hist_kernel(const int* __restrict__ dst, int* __restrict__ deg)
{
    int e = blockIdx.x * 256 + threadIdx.x;
    if (e < N_EDGES) atomicAdd(&deg[dst[e]], 1);
}

__global__ void scan1_kernel(const int* __restrict__ deg, int* __restrict__ off,
                             int* __restrict__ bsum)
{
    __shared__ int sm[256];
    int i = blockIdx.x * 256 + threadIdx.x;
    int v = (i < N_NODES) ? deg[i] : 0;
    sm[threadIdx.x] = v;
    __syncthreads();
    #pragma unroll
    for (int d = 1; d < 256; d <<= 1) {
        int t = (threadIdx.x >= d) ? sm[threadIdx.x - d] : 0;
        __syncthreads();
        sm[threadIdx.x] += t;
        __syncthreads();
    }
    if (i < N_NODES) off[i] = sm[threadIdx.x] - v;
    if (threadIdx.x == 255) bsum[blockIdx.x] = sm[255];
}

__global__ void scan2_kernel(int* __restrict__ bsum, int nb)
{
    __shared__ int sm[256];
    int v = (threadIdx.x < nb) ? bsum[threadIdx.x] : 0;
    sm[threadIdx.x] = v;
    __syncthreads();
    #pragma unroll
    for (int d = 1; d < 256; d <<= 1) {
        int t = (threadIdx.x >= d) ? sm[threadIdx.x - d] : 0;
        __syncthreads();
        sm[threadIdx.x] += t;
        __syncthreads();
    }
    if (threadIdx.x < nb) bsum[threadIdx.x] = sm[threadIdx.x] - v;
}

__global__ void scan3_kernel(int* __restrict__ off, const int* __restrict__ bsum,
                             int* __restrict__ cursor)
{
    int i = blockIdx.x * 256 + threadIdx.x;
    if (i < N_NODES) {
        int o = off[i] + bsum[blockIdx.x];
        off[i] = o;
        cursor[i] = o;
    }
}

// scatter: src id + bf16 edge_attr row in destination-sorted order
// (random writes here buy SEQUENTIAL hot-loop reads in node_attn — r6 lesson)
__global__ void scatter_kernel(const int* __restrict__ dst, const int* __restrict__ src,
                               const float* __restrict__ eattr, int* __restrict__ cursor,
                               int* __restrict__ src_s, ushort* __restrict__ eattr_s)
{
    int e = blockIdx.x * 256 + threadIdx.x;
    if (e < N_EDGES) {
        int p = atomicAdd(&cursor[dst[e]], 1);
        src_s[p] = src[e];
        const float4* s4 = (const float4*)(eattr + (size_t)e * E_DIM);
        float4 f0 = s4[0], f1 = s4[1], f2 = s4[2], f3 = s4[3];
        uint4 u0, u1;
        u0.x = pack2(f0.x, f0.y); u0.y = pack2(f0.z, f0.w);
        u0.z = pack2(f1.x, f1.y); u0.w = pack2(f1.z, f1.w);
        u1.x = pack2(f2.x, f2.y); u1.y = pack2(f2.z, f2.w);
        u1.z = pack2(f3.x, f3.y); u1.w = pack2(f3.z, f3.w);
        uint4* d4 = (uint4*)(eattr_s + (size_t)p * E_DIM);
        d4[0] = u0; d4[1] = u1;
    }
}

// ---------------- Fused node attention + beta + residual + LN2 (r12 EXACT) --------
// Lane l owns head h = l>>3, channels 2l, 2l+1 (j = l&7 -> ea comps 2j, 2j+1).
// 2-way unroll with DUAL accumulator state (r8/r10 lessons: do not restructure).
#define ATTN_STEP(P, S, A0, A1, E0, E1) do {                                         \
    int sv_ = src_s[P];                                                              \
    uint eap_ = *(const uint*)(eattr_s + (size_t)(P) * E_DIM + j2);                  \
    float ea0_ = bf2f((ushort)eap_), ea1_ = bf2f((ushort)(eap_ >> 16));              \
    size_t sb_ = (size_t)sv_ * 512;                                                  \
    uint kp_ = *(const uint*)(qkvs + sb_ + 128 + 2 * lane);                          \
    uint vp_ = *(const uint*)(qkvs + sb_ + 256 + 2 * lane);                          \
    float p_ = q0 * bf2f((ushort)kp_) + q1 * bf2f((ushort)(kp_ >> 16))               \
             + ea0_ * qp0 + ea1_ * qp1;                                              \
    p_ += __shfl_xor(p_, 1, 64);                                                     \
    p_ += __shfl_xor(p_, 2, 64);                                                     \
    p_ += __shfl_xor(p_, 4, 64);                                                     \
    float w_ = __expf(fminf(p_, 60.f));                                              \
    S  += w_;                                                                        \
    A0 += w_ * bf2f((ushort)vp_);                                                    \
    A1 += w_ * bf2f((ushort)(vp_ >> 16));                                            \
    E0 += w_ * ea0_;                                                                 \
    E1 += w_ * ea1_;                                                                 \
} while (0)

__global__ void node_attn(const ushort* __restrict__ qkvs, const float* __restrict__ x,
                          const float* __restrict__ we, const float* __restrict__ wbeta,
                          const float* __restrict__ ln2g, const float* __restrict__ ln2b,
                          const int* __restrict__ off, const int* __restrict__ deg,
                          const int* __restrict__ src_s, const ushort* __restrict__ eattr_s,
                          float* __restrict__ xnew, ushort* __restrict__ h2)
{
    __shared__ float wl[E_DIM * 128];     // we row-major [16][128], 8 KB
    __shared__ float weT[128 * 17];       // we transposed [128][16+pad], 8.5 KB
    __shared__ float sc4[4][128];         // per-wave scratch, 2 KB
    for (int t = threadIdx.x; t < E_DIM * 32; t += 256)
        *(float4*)&wl[t * 4] = *(const float4*)&we[t * 4];
    for (int t = threadIdx.x; t < E_DIM * 128; t += 256) {
        int j = t >> 7, ch = t & 127;
        weT[ch * 17 + j] = we[t];
    }
    __syncthreads();

    int nl   = threadIdx.x >> 6;
    int node = blockIdx.x * 4 + nl;
    int lane = threadIdx.x & 63;
    if (node >= N_NODES) return;

    int j2 = (lane & 7) * 2;              // this lane's ea component pair
    int hb = (lane >> 3) * 16;            // head channel base

    size_t nb = (size_t)node * 512;
    uint qp = *(const uint*)(qkvs + nb + 2 * lane);
    float q0r = bf2f((ushort)qp), q1r = bf2f((ushort)(qp >> 16));

    sc4[nl][2 * lane]     = q0r;
    sc4[nl][2 * lane + 1] = q1r;
    float qp0 = 0.f, qp1 = 0.f;
    #pragma unroll
    for (int c = 0; c < 16; ++c) {
        float qc = sc4[nl][hb + c];
        qp0 += qc * weT[(hb + c) * 17 + j2];
        qp1 += qc * weT[(hb + c) * 17 + j2 + 1];
    }
    float q0 = q0r * 0.25f, q1 = q1r * 0.25f;   // fold 1/sqrt(C)
    qp0 *= 0.25f; qp1 *= 0.25f;

    float SA = 0.f, A0a = 0.f, A1a = 0.f, E0a = 0.f, E1a = 0.f;
    float SB = 0.f, A0b = 0.f, A1b = 0.f, E0b = 0.f, E1b = 0.f;

    int o = off[node], dg = deg[node];
    int i = 0;
    for (; i + 2 <= dg; i += 2) {
        ATTN_STEP(o + i,     SA, A0a, A1a, E0a, E1a);
        ATTN_STEP(o + i + 1, SB, A0b, A1b, E0b, E1b);
    }
    if (i < dg)
        ATTN_STEP(o + i, SA, A0a, A1a, E0a, E1a);

    float S  = SA + SB;
    float A0 = A0a + A0b, A1 = A1a + A1b;
    float E0 = E0a + E0b, E1 = E1a + E1b;

    sc4[nl][2 * lane]     = E0;
    sc4[nl][2 * lane + 1] = E1;
    float ep0 = 0.f, ep1 = 0.f;
    #pragma unroll
    for (int j = 0; j < 16; ++j) {
        float es = sc4[nl][hb + j];
        ep0 += es * wl[j * 128 + 2 * lane];
        ep1 += es * wl[j * 128 + 2 * lane + 1];
    }

    float rinv = 1.f / (S + 1e-16f);
    float o0 = (A0 + ep0) * rinv;
    float o1 = (A1 + ep1) * rinv;

    uint xrp = *(const uint*)(qkvs + nb + 384 + 2 * lane);
    float xr0 = bf2f((ushort)xrp), xr1 = bf2f((ushort)(xrp >> 16));
    float2 wb0 = *(const float2*)&wbeta[2 * lane];
    float2 wb1 = *(const float2*)&wbeta[128 + 2 * lane];
    float2 wb2 = *(const float2*)&wbeta[256 + 2 * lane];
    float dot = o0 * wb0.x + o1 * wb0.y + xr0 * wb1.x + xr1 * wb1.y
              + (o0 - xr0) * wb2.x + (o1 - xr1) * wb2.y;
    #pragma unroll
    for (int w = 32; w > 0; w >>= 1) dot += __shfl_xor(dot, w, 64);
    float beta = 1.f / (1.f + __expf(-dot));

    size_t xb = (size_t)node * D_MODEL + 2 * lane;
    float2 xv = *(const float2*)&x[xb];
    float ox = xv.x + beta * xr0 + (1.f - beta) * o0;
    float oy = xv.y + beta * xr1 + (1.f - beta) * o1;
    *(float2*)&xnew[xb] = make_float2(ox, oy);

    // ---- fused LN2 ----
    float s2  = ox + oy;
    float ss2 = ox * ox + oy * oy;
    #pragma unroll
    for (int w = 32; w > 0; w >>= 1) {
        s2  += __shfl_xor(s2,  w, 64);
        ss2 += __shfl_xor(ss2, w, 64);
    }
    float mu  = s2 * (1.0f / 128.0f);
    float var = ss2 * (1.0f / 128.0f) - mu * mu;
    float rs  = rsqrtf(var + 1e-5f);
    float2 g2 = *(const float2*)&ln2g[2 * lane];
    float2 b2 = *(const float2*)&ln2b[2 * lane];
    float h0 = (ox - mu) * rs * g2.x + b2.x;
    float h1 = (oy - mu) * rs * g2.y + b2.y;
    ((uint*)h2)[(size_t)node * 64 + lane] = pack2(h0, h1);
}

extern "C" void kernel_launch(void* const* d_in, const int* in_sizes, int n_in,
                              void* d_out, int out_size, void* d_ws, size_t ws_size,
                              hipStream_t stream)
{
    const float* x     = (const float*)d_in[0];
    const int*   eidx  = (const int*)  d_in[1];
    const float* eattr = (const float*)d_in[2];
    const float* wq  = (const float*)d_in[3];  const float* bq  = (const float*)d_in[4];
    const float* wk  = (const float*)d_in[5];  const float* bk  = (const float*)d_in[6];
    const float* wv  = (const float*)d_in[7];  const float* bv  = (const float*)d_in[8];
    const float* we  = (const float*)d_in[9];
    const float* wsk = (const float*)d_in[10]; const float* bsk = (const float*)d_in[11];
    const float* wbeta = (const float*)d_in[12];
    const float* ln1g = (const float*)d_in[13]; const float* ln1b = (const float*)d_in[14];
    const float* ln2g = (const float*)d_in[15]; const float* ln2b = (const float*)d_in[16];
    const float* w1 = (const float*)d_in[17]; const float* b1 = (const float*)d_in[18];
    const float* w2 = (const float*)d_in[19]; const float* b2 = (const float*)d_in[20];
    const int* srcp = eidx;
    const int* dstp = eidx + N_EDGES;
    float* out = (float*)d_out;

    char* w = (char*)d_ws;
    size_t o = 0;
    ushort* qkvs_b  = (ushort*)(w + o);  o += (size_t)N_NODES * 512 * 2;   // 51.2MB
    float* xnew = (float*)(w + o);  o += (size_t)N_NODES * 128 * 4;        // 25.6MB
    ushort* eattr_s = (ushort*)(w + o); o += (size_t)N_EDGES * E_DIM * 2;  // 25.6MB
    int* src_s = (int*)(w + o);     o += (size_t)N_EDGES * 4;              // 3.2MB
    ushort* h2_b = (ushort*)(w + o); o += (size_t)N_NODES * 128 * 2;       // 12.8MB
    ushort* wqkvsT = (ushort*)(w + o); o += 512 * 128 * 2;
    ushort* w1T    = (ushort*)(w + o); o += 256 * 128 * 2;
    ushort* w2T    = (ushort*)(w + o); o += 128 * 256 * 2;
    float*  bqkvs  = (float*)(w + o);  o += 4096;
    int* deg    = (int*)(w + o); o += 200704;
    int* offb   = (int*)(w + o); o += 200704;
    int* cursor = (int*)(w + o); o += 200704;
    int* bsum   = (int*)(w + o); o += 4096;

    dim3 blk(256);
    dim3 lngrid((N_NODES + 3) / 4);
    const int NB = (N_NODES + 255) / 256;
    const int EB = (N_EDGES + 255) / 256;
    const int GB = (N_NODES + 127) / 128;

    prep_weights<<<dim3(256), blk, 0, stream>>>(wq, wk, wv, wsk, bq, bk, bv, bsk,
                                                w1, w2, wqkvsT, bqkvs, w1T, w2T, deg);
    proj_ln_gemm<<<dim3(GB, 4), blk, 0, stream>>>(x, ln1g, ln1b, wqkvsT, bqkvs,
                                                  qkvs_b, N_NODES);
    hist_kernel<<<dim3(EB), blk, 0, stream>>>(dstp, deg);
    scan1_kernel<<<dim3(NB), blk, 0, stream>>>(deg, offb, bsum);
    scan2_kernel<<<dim3(1), blk, 0, stream>>>(bsum, NB);
    scan3_kernel<<<dim3(NB), blk, 0, stream>>>(offb, bsum, cursor);
    scatter_kernel<<<dim3(EB), blk, 0, stream>>>(dstp, srcp, eattr, cursor, src_s, eattr_s);
    node_attn<<<lngrid, blk, 0, stream>>>(qkvs_b, x, we, wbeta, ln2g, ln2b,
                                          offb, deg, src_s, eattr_s, xnew, h2_b);
    ffn_fused<<<dim3(GB), blk, 0, stream>>>(h2_b, w1T, w2T, b1, b2, xnew, out, N_NODES);
}